// Round 10
// baseline (272.328 us; speedup 1.0000x reference)
//
#include <hip/hip_runtime.h>

#define F1 128
#define F2 64
// bucket = 512 consecutive nodes; requires N <= 256*512 and N < 2^17 (u32 pack)
#define BSH 9
#define BSZ 512
// LDS staging capacity for one bucket's edge list in k_bfill (48 KB).
#define BFILL_CAP 12288
// edges staged per block in the partition branch of k_pg
#define PSTAGE 4096

typedef unsigned int u32;
typedef unsigned short u16;
typedef __attribute__((ext_vector_type(8))) short bf16x8;   // 8 bf16 (4 VGPRs)
typedef __attribute__((ext_vector_type(4))) float f32x4;

// bf16 helpers (manual, header-version-proof). RNE pack, shift unpack.
__device__ __forceinline__ u32 bf16rne(float f) {
    u32 u = __float_as_uint(f);
    return (u + 0x7FFFu + ((u >> 16) & 1u)) >> 16;
}
__device__ __forceinline__ u32 pack2(float lo, float hi) {
    return bf16rne(lo) | (bf16rne(hi) << 16);
}
__device__ __forceinline__ float bflo(u32 u) { return __uint_as_float(u << 16); }
__device__ __forceinline__ float bfhi(u32 u) { return __uint_as_float(u & 0xFFFF0000u); }

__device__ __forceinline__ void acc8(float* ax, uint4 v) {
    ax[0] += bflo(v.x); ax[1] += bfhi(v.x);
    ax[2] += bflo(v.y); ax[3] += bfhi(v.y);
    ax[4] += bflo(v.z); ax[5] += bfhi(v.z);
    ax[6] += bflo(v.w); ax[7] += bfhi(v.w);
}

// ax += w * row  (per-source normalized accumulate)
__device__ __forceinline__ void facc8(float* ax, uint4 v, float w) {
    ax[0] = fmaf(w, bflo(v.x), ax[0]); ax[1] = fmaf(w, bfhi(v.x), ax[1]);
    ax[2] = fmaf(w, bflo(v.y), ax[2]); ax[3] = fmaf(w, bfhi(v.y), ax[3]);
    ax[4] = fmaf(w, bflo(v.z), ax[4]); ax[5] = fmaf(w, bfhi(v.z), ax[5]);
    ax[6] = fmaf(w, bflo(v.w), ax[6]); ax[7] = fmaf(w, bfhi(v.w), ax[7]);
}

// ---------------- W prep helper ----------------
// Frag layout for mfma_f32_16x16x32_bf16 B-operand: n = lane&15, k = (lane>>4)*8 + j.

__device__ __forceinline__ void wprep_do(const float* __restrict__ W,
                                         uint4* __restrict__ wf, int NBc, int t) {
    int lane = t & 63;
    int rem = t >> 6;
    int nb = rem % NBc;
    int kb = rem / NBc;
    int C = NBc * 16;
    int col = nb * 16 + (lane & 15);
    int krow = kb * 32 + (lane >> 4) * 8;
    u32 w[4];
#pragma unroll
    for (int p = 0; p < 4; p++) {
        float lo = W[(size_t)(krow + 2 * p) * C + col];
        float hi = W[(size_t)(krow + 2 * p + 1) * C + col];
        w[p] = pack2(lo, hi);
    }
    wf[t] = make_uint4(w[0], w[1], w[2], w[3]);
}

// ---------------- Fused: bucket histogram + W prep ----------------
// Blocks 0..255: bucket hist (LDS-aggregated). Blocks 256..267: W1/W2 prep.

__global__ __launch_bounds__(256) void k_hw(const int* __restrict__ colv,
                                            int* __restrict__ bucket_cnt,
                                            const float* __restrict__ W1,
                                            const float* __restrict__ W2,
                                            uint4* __restrict__ w1f,
                                            uint4* __restrict__ w2f, int E) {
    __shared__ int l[256];
    int blk = blockIdx.x;
    int t = threadIdx.x;
    if (blk < 256) {
        l[t] = 0;
        __syncthreads();
        for (int e = blk * 256 + t; e < E; e += 256 * 256)
            atomicAdd(&l[colv[e] >> BSH], 1);
        __syncthreads();
        if (l[t]) atomicAdd(&bucket_cnt[t], l[t]);
    } else {
        int b2 = blk - 256;
        if (b2 < 8) wprep_do(W1, w1f, 8, b2 * 256 + t);
        else        wprep_do(W2, w2f, 4, (b2 - 8) * 256 + t);
    }
}

// ---------------- Fused: edge partition (bucket sort) || GEMM1 (raw) ----------------
// Blocks [0, PB): stage PSTAGE edges, block-local counting sort by bucket into
// LDS, reserve per-bucket runs with one global atomic each, write runs out
// coalesced (bucket bases recomputed by scanning bucket_cnt). 16-edge runs
// (PSTAGE/256) give 64 B write granules.
// Blocks [PB, PB+gblocks): g1raw(bf16, row-major) = x @ W1 (UNSCALED -- the
// per-source dis scale is applied during agg1's gather, removing the CSR->gemm1
// dependency so the two branches overlap).

__global__ __launch_bounds__(256, 4) void k_pg(const int* __restrict__ rowv,
                                               const int* __restrict__ colv,
                                               const int* __restrict__ bucket_cnt,
                                               int* __restrict__ bucket_cur,
                                               u32* __restrict__ ebuf, int E, int PB,
                                               const float* __restrict__ x,
                                               const uint4* __restrict__ w1f,
                                               u16* __restrict__ gb, int N) {
    if ((int)blockIdx.x < PB) {
        __shared__ int lcnt[256], lexcl[256], lcur[256], lbase[256], gscan[256];
        __shared__ int stot;
        __shared__ u32 sval[PSTAGE];
        __shared__ u16 sbkt[PSTAGE];
        int t = threadIdx.x;
        lcnt[t] = 0;
        __syncthreads();
        int rows[16], cols[16];
        int e0 = blockIdx.x * PSTAGE;
#pragma unroll
        for (int it = 0; it < 16; it++) {
            int e = e0 + it * 256 + t;
            bool v = e < E;
            cols[it] = v ? colv[e] : -1;
            rows[it] = v ? rowv[e] : 0;
            if (v) atomicAdd(&lcnt[cols[it] >> BSH], 1);
        }
        int bc = bucket_cnt[t];
        __syncthreads();
        int v = lcnt[t];
        lexcl[t] = v;
        gscan[t] = bc;
        __syncthreads();
        for (int d = 1; d < 256; d <<= 1) {
            int u1 = (t >= d) ? lexcl[t - d] : 0;
            int u2 = (t >= d) ? gscan[t - d] : 0;
            __syncthreads();
            lexcl[t] += u1;
            gscan[t] += u2;
            __syncthreads();
        }
        int incl = lexcl[t];
        int gincl = gscan[t];
        __syncthreads();
        lexcl[t] = incl - v;
        lcur[t] = incl - v;
        if (v) lbase[t] = (gincl - bc) + atomicAdd(&bucket_cur[t], v);
        if (t == 255) stot = incl;
        __syncthreads();
#pragma unroll
        for (int it = 0; it < 16; it++) {
            if (cols[it] >= 0) {
                int b = cols[it] >> BSH;
                int pos = atomicAdd(&lcur[b], 1);
                sval[pos] = ((u32)(cols[it] & (BSZ - 1)) << 17) | (u32)rows[it];
                sbkt[pos] = (u16)b;
            }
        }
        __syncthreads();
        int total = stot;
        for (int i = t; i < total; i += 256) {
            int b = sbkt[i];
            ebuf[lbase[b] + (i - lexcl[b])] = sval[i];
        }
    } else {
        int bid = (int)blockIdx.x - PB;
        int lane = threadIdx.x & 63;
        int wave = threadIdx.x >> 6;
        int m = lane & 15, quad = lane >> 4;
        int row0 = bid * 64 + wave * 16;
        int arow = min(row0 + m, N - 1);
        const float* xr = x + (size_t)arow * F1 + quad * 8;
        bf16x8 a[4];
#pragma unroll
        for (int kb = 0; kb < 4; kb++) {
            float4 lo = *(const float4*)(xr + kb * 32);
            float4 hi = *(const float4*)(xr + kb * 32 + 4);
            a[kb][0] = (short)bf16rne(lo.x); a[kb][1] = (short)bf16rne(lo.y);
            a[kb][2] = (short)bf16rne(lo.z); a[kb][3] = (short)bf16rne(lo.w);
            a[kb][4] = (short)bf16rne(hi.x); a[kb][5] = (short)bf16rne(hi.y);
            a[kb][6] = (short)bf16rne(hi.z); a[kb][7] = (short)bf16rne(hi.w);
        }
        f32x4 acc[8];
#pragma unroll
        for (int nb = 0; nb < 8; nb++) acc[nb] = (f32x4)(0.0f);
#pragma unroll
        for (int nb = 0; nb < 8; nb++) {
#pragma unroll
            for (int kb = 0; kb < 4; kb++) {
                uint4 braw = w1f[(kb * 8 + nb) * 64 + lane];
                bf16x8 bf = *(bf16x8*)&braw;
                acc[nb] = __builtin_amdgcn_mfma_f32_16x16x32_bf16(a[kb], bf, acc[nb], 0, 0, 0);
            }
        }
        // epilogue: C layout col = lane&15, row = quad*4 + reg; raw (no dis)
        int rbase = row0 + quad * 4;
#pragma unroll
        for (int reg = 0; reg < 4; reg++) {
            int r = rbase + reg;
            if (r < N) {
                u16* gr = gb + (size_t)r * F1 + m;
#pragma unroll
                for (int nb = 0; nb < 8; nb++)
                    gr[nb * 16] = (u16)bf16rne(acc[nb][reg]);
            }
        }
    }
}

// ---------------- bfill: per-bucket counting sort -> rowptr, dis, adj ----------------
// One 1024-thread block per bucket (edge loops 2x wider than the 512 version;
// scans guarded to the first 512/256 threads).

__global__ __launch_bounds__(1024) void k_bfill(const u32* __restrict__ ebuf,
                                                const int* __restrict__ bucket_cnt,
                                                int* __restrict__ rowptr,
                                                float* __restrict__ dis,
                                                int* __restrict__ adj, int N, int E) {
    __shared__ int cnt[BSZ], scn[BSZ], cur[BSZ];
    __shared__ int bb[256];
    __shared__ int sadj[BFILL_CAP];
    int t = threadIdx.x;
    int b = blockIdx.x;
    if (t < 256) bb[t] = bucket_cnt[t];
    if (t < BSZ) cnt[t] = 0;
    __syncthreads();
    for (int d = 1; d < 256; d <<= 1) {
        int u = (t >= d && t < 256) ? bb[t - d] : 0;
        __syncthreads();
        if (t < 256) bb[t] += u;
        __syncthreads();
    }
    int e1 = bb[b];
    int e0 = e1 - bucket_cnt[b];
    int len = e1 - e0;
    if (b == 0 && t == 0) rowptr[N] = E;
    for (int i = e0 + t; i < e1; i += 1024)
        atomicAdd(&cnt[ebuf[i] >> 17], 1);
    __syncthreads();
    if (t < BSZ) scn[t] = cnt[t];
    __syncthreads();
    for (int d = 1; d < BSZ; d <<= 1) {
        int u = (t >= d && t < BSZ) ? scn[t - d] : 0;
        __syncthreads();
        if (t < BSZ) scn[t] += u;
        __syncthreads();
    }
    if (t < BSZ) {
        int excl = scn[t] - cnt[t];
        cur[t] = excl;
        int node = (b << BSH) + t;
        if (node < N) {
            rowptr[node] = e0 + excl;
            dis[node] = rsqrtf((float)(cnt[t] + 1));   // +1 self loop
        }
    }
    __syncthreads();
    if (len <= BFILL_CAP) {
        for (int i = e0 + t; i < e1; i += 1024) {
            u32 p = ebuf[i];
            int c = p >> 17;
            int pos = atomicAdd(&cur[c], 1);
            sadj[pos] = (int)(p & 0x1FFFFu);
        }
        __syncthreads();
        for (int i = t; i < len; i += 1024)
            adj[e0 + i] = sadj[i];
    } else {
        for (int i = e0 + t; i < e1; i += 1024) {
            u32 p = ebuf[i];
            int c = p >> 17;
            int pos = atomicAdd(&cur[c], 1);
            adj[e0 + pos] = (int)(p & 0x1FFFFu);
        }
    }
}

// ---------------- Aggregation 1: z = relu(dis_i*(dis_i*g1raw[i] + sum dis_src*g1raw[src]) + b1) ----------------
// Wave = 1 node. 4 lane-groups of 16; each group gathers one full 256B source
// row (16 lanes x uint4) and its source's dis (4B broadcast). 2 chunks in
// flight, exec-masked, adj+dis prefetch; adj read nontemporally (keep L2 for
// the gather table). Cross-group reduce: shfl_xor 16, 32.

__global__ __launch_bounds__(256) void k_agg1(const uint4* __restrict__ g1,
                                              const int* __restrict__ rowptr,
                                              const int* __restrict__ adj,
                                              const float* __restrict__ dis,
                                              const float* __restrict__ b,
                                              uint4* __restrict__ z, int N) {
    int node = __builtin_amdgcn_readfirstlane(blockIdx.x * 4 + (threadIdx.x >> 6));
    if (node >= N) return;
    int lane = threadIdx.x & 63;
    int grp = lane >> 4;        // 0..3
    int sub = lane & 15;        // col chunk: cols [8*sub, 8*sub+8)
    float ax[8];
#pragma unroll
    for (int i = 0; i < 8; i++) ax[i] = 0.0f;
    int s = rowptr[node], e = rowptr[node + 1];
    float dnode = dis[node];
    if (grp == 0) facc8(ax, g1[(size_t)node * 16 + sub], dnode);   // self-loop term
    const uint4 z4 = make_uint4(0u, 0u, 0u, 0u);
    int i0 = s + grp;
    bool p0 = i0 < e, p1 = i0 + 4 < e, p2 = i0 + 8 < e, p3 = i0 + 12 < e;
    int c0 = 0, c1 = 0, c2 = 0, c3 = 0;
    float d0 = 0.0f, d1 = 0.0f, d2 = 0.0f, d3 = 0.0f;
    if (p0) { c0 = __builtin_nontemporal_load(adj + i0);      d0 = dis[c0]; }
    if (p1) { c1 = __builtin_nontemporal_load(adj + i0 + 4);  d1 = dis[c1]; }
    if (p2) { c2 = __builtin_nontemporal_load(adj + i0 + 8);  d2 = dis[c2]; }
    if (p3) { c3 = __builtin_nontemporal_load(adj + i0 + 12); d3 = dis[c3]; }
    for (int j = s; j < e; j += 16) {
        uint4 v0 = z4, v1 = z4, v2 = z4, v3 = z4;
        if (p0) v0 = g1[(size_t)c0 * 16 + sub];
        if (p1) v1 = g1[(size_t)c1 * 16 + sub];
        if (p2) v2 = g1[(size_t)c2 * 16 + sub];
        if (p3) v3 = g1[(size_t)c3 * 16 + sub];
        float w0 = d0, w1 = d1, w2 = d2, w3 = d3;
        int in0 = j + 16 + grp;
        p0 = in0 < e; p1 = in0 + 4 < e; p2 = in0 + 8 < e; p3 = in0 + 12 < e;
        d0 = 0.0f; d1 = 0.0f; d2 = 0.0f; d3 = 0.0f;
        if (p0) { c0 = __builtin_nontemporal_load(adj + in0);      d0 = dis[c0]; }
        if (p1) { c1 = __builtin_nontemporal_load(adj + in0 + 4);  d1 = dis[c1]; }
        if (p2) { c2 = __builtin_nontemporal_load(adj + in0 + 8);  d2 = dis[c2]; }
        if (p3) { c3 = __builtin_nontemporal_load(adj + in0 + 12); d3 = dis[c3]; }
        facc8(ax, v0, w0);
        facc8(ax, v1, w1);
        facc8(ax, v2, w2);
        facc8(ax, v3, w3);
    }
#pragma unroll
    for (int i = 0; i < 8; i++) {
        ax[i] += __shfl_xor(ax[i], 16);
        ax[i] += __shfl_xor(ax[i], 32);
    }
    if (grp == 0) {
        float4 b0 = *(const float4*)(b + 8 * sub);
        float4 b1 = *(const float4*)(b + 8 * sub + 4);
        float o[8];
        o[0] = fmaxf(fmaf(dnode, ax[0], b0.x), 0.0f);
        o[1] = fmaxf(fmaf(dnode, ax[1], b0.y), 0.0f);
        o[2] = fmaxf(fmaf(dnode, ax[2], b0.z), 0.0f);
        o[3] = fmaxf(fmaf(dnode, ax[3], b0.w), 0.0f);
        o[4] = fmaxf(fmaf(dnode, ax[4], b1.x), 0.0f);
        o[5] = fmaxf(fmaf(dnode, ax[5], b1.y), 0.0f);
        o[6] = fmaxf(fmaf(dnode, ax[6], b1.z), 0.0f);
        o[7] = fmaxf(fmaf(dnode, ax[7], b1.w), 0.0f);
        uint4 ov;
        ov.x = pack2(o[0], o[1]); ov.y = pack2(o[2], o[3]);
        ov.z = pack2(o[4], o[5]); ov.w = pack2(o[6], o[7]);
        z[(size_t)node * 16 + sub] = ov;
    }
}

// ---------------- GEMM 2 (MFMA): g2(bf16, row-major) = dis[row] * (z @ W2) ----------------

__global__ __launch_bounds__(256, 4) void k_gemm2(const u32* __restrict__ z,
                                                  const uint4* __restrict__ w2f,
                                                  const float* __restrict__ dis,
                                                  u16* __restrict__ gb, int N) {
    int lane = threadIdx.x & 63;
    int wave = threadIdx.x >> 6;
    int m = lane & 15, quad = lane >> 4;
    int row0 = blockIdx.x * 64 + wave * 16;
    int arow = min(row0 + m, N - 1);
    const u32* zr = z + (size_t)arow * 64 + quad * 4;
    bf16x8 a[4];
#pragma unroll
    for (int kb = 0; kb < 4; kb++) {
        uint4 za = *(const uint4*)(zr + kb * 16);
        a[kb] = *(bf16x8*)&za;
    }
    f32x4 acc[4];
#pragma unroll
    for (int nb = 0; nb < 4; nb++) acc[nb] = (f32x4)(0.0f);
#pragma unroll
    for (int nb = 0; nb < 4; nb++) {
#pragma unroll
        for (int kb = 0; kb < 4; kb++) {
            uint4 braw = w2f[(kb * 4 + nb) * 64 + lane];
            bf16x8 bf = *(bf16x8*)&braw;
            acc[nb] = __builtin_amdgcn_mfma_f32_16x16x32_bf16(a[kb], bf, acc[nb], 0, 0, 0);
        }
    }
    float dv[4];
    int rbase = row0 + quad * 4;
#pragma unroll
    for (int reg = 0; reg < 4; reg++) dv[reg] = dis[min(rbase + reg, N - 1)];
#pragma unroll
    for (int reg = 0; reg < 4; reg++) {
        int r = rbase + reg;
        if (r < N) {
            u16* gr = gb + (size_t)r * F2 + m;
#pragma unroll
            for (int nb = 0; nb < 4; nb++)
                gr[nb * 16] = (u16)bf16rne(acc[nb][reg] * dv[reg]);
        }
    }
}

// ---------------- Aggregation 2: out(fp32) = dis[i]*(g2[i] + sum g2[src]) + b2 ----------------
// Wave = 1 node. 8 lane-groups of 8; each group gathers one 128B source row.
// 4 chunks (32 edges) in flight, exec-masked, nontemporal adj prefetch.
// Reduce: shfl_xor 8, 16, 32.

__global__ __launch_bounds__(256) void k_agg2(const uint4* __restrict__ g,
                                              const int* __restrict__ rowptr,
                                              const int* __restrict__ adj,
                                              const float* __restrict__ dis,
                                              const float* __restrict__ b,
                                              float* __restrict__ out, int N) {
    int node = __builtin_amdgcn_readfirstlane(blockIdx.x * 4 + (threadIdx.x >> 6));
    if (node >= N) return;
    int lane = threadIdx.x & 63;
    int grp = lane >> 3;        // 0..7
    int sub = lane & 7;         // col chunk: cols [8*sub, 8*sub+8)
    float ax[8];
#pragma unroll
    for (int i = 0; i < 8; i++) ax[i] = 0.0f;
    int s = rowptr[node], e = rowptr[node + 1];
    if (grp == 0) acc8(ax, g[(size_t)node * 8 + sub]);   // self-loop term
    const uint4 z4 = make_uint4(0u, 0u, 0u, 0u);
    int i0 = s + grp;
    bool p0 = i0 < e, p1 = i0 + 8 < e, p2 = i0 + 16 < e, p3 = i0 + 24 < e;
    int c0 = 0, c1 = 0, c2 = 0, c3 = 0;
    if (p0) c0 = __builtin_nontemporal_load(adj + i0);
    if (p1) c1 = __builtin_nontemporal_load(adj + i0 + 8);
    if (p2) c2 = __builtin_nontemporal_load(adj + i0 + 16);
    if (p3) c3 = __builtin_nontemporal_load(adj + i0 + 24);
    for (int j = s; j < e; j += 32) {
        uint4 v0 = z4, v1 = z4, v2 = z4, v3 = z4;
        if (p0) v0 = g[(size_t)c0 * 8 + sub];
        if (p1) v1 = g[(size_t)c1 * 8 + sub];
        if (p2) v2 = g[(size_t)c2 * 8 + sub];
        if (p3) v3 = g[(size_t)c3 * 8 + sub];
        int in0 = j + 32 + grp;
        p0 = in0 < e; p1 = in0 + 8 < e; p2 = in0 + 16 < e; p3 = in0 + 24 < e;
        if (p0) c0 = __builtin_nontemporal_load(adj + in0);
        if (p1) c1 = __builtin_nontemporal_load(adj + in0 + 8);
        if (p2) c2 = __builtin_nontemporal_load(adj + in0 + 16);
        if (p3) c3 = __builtin_nontemporal_load(adj + in0 + 24);
        acc8(ax, v0);
        acc8(ax, v1);
        acc8(ax, v2);
        acc8(ax, v3);
    }
#pragma unroll
    for (int i = 0; i < 8; i++) {
        ax[i] += __shfl_xor(ax[i], 8);
        ax[i] += __shfl_xor(ax[i], 16);
        ax[i] += __shfl_xor(ax[i], 32);
    }
    if (grp == 0) {
        float d = dis[node];
        float4 b0 = *(const float4*)(b + 8 * sub);
        float4 b1 = *(const float4*)(b + 8 * sub + 4);
        float4 o0, o1;
        o0.x = fmaf(d, ax[0], b0.x); o0.y = fmaf(d, ax[1], b0.y);
        o0.z = fmaf(d, ax[2], b0.z); o0.w = fmaf(d, ax[3], b0.w);
        o1.x = fmaf(d, ax[4], b1.x); o1.y = fmaf(d, ax[5], b1.y);
        o1.z = fmaf(d, ax[6], b1.z); o1.w = fmaf(d, ax[7], b1.w);
        float4* op = (float4*)(out + (size_t)node * F2 + 8 * sub);
        op[0] = o0;
        op[1] = o1;
    }
}

// ---------------- launch ----------------

extern "C" void kernel_launch(void* const* d_in, const int* in_sizes, int n_in,
                              void* d_out, int out_size, void* d_ws, size_t ws_size,
                              hipStream_t stream) {
    const float* x  = (const float*)d_in[0];
    const int*   ei = (const int*)d_in[1];
    const float* W1 = (const float*)d_in[2];
    const float* b1 = (const float*)d_in[3];
    const float* W2 = (const float*)d_in[4];
    const float* b2 = (const float*)d_in[5];
    float* out = (float*)d_out;

    const int N = in_sizes[0] / F1;
    const int E = in_sizes[1] / 2;
    const int NB = (N + BSZ - 1) >> BSH;   // 196 for N=100000; must be <= 256
    const int* rowv = ei;        // sources
    const int* colv = ei + E;    // targets

    char* ws = (char*)d_ws;
    size_t off = 0;
    auto take = [&](size_t bytes) -> void* {
        void* p = ws + off;
        off += (bytes + 255) & ~(size_t)255;
        return p;
    };
    u16*   g1b     = (u16*)take((size_t)N * F1 * 2);   // 25.6 MB (bf16 row-major, RAW x@W1)
    u32*   zb      = (u32*)take((size_t)N * 64 * 4);   // 25.6 MB (bf16 packed)
    u16*   g2b     = g1b;                // g1 dead after agg1 -> reuse
    u32*   ebuf    = zb;                 // ebuf (6.4 MB) dead before agg1 writes zb;
                                         // separate from g1b (gemm1 runs concurrent with part)
    float* dis     = (float*)take((size_t)N * 4);
    int*   rowptr  = (int*)take((size_t)(N + 1) * 4);
    int*   adj     = (int*)take((size_t)E * 4);        // 6.4 MB
    uint4* w1f     = (uint4*)take(4 * 8 * 64 * 16);    // 32 KB bf16 frag-order W1
    uint4* w2f     = (uint4*)take(4 * 4 * 64 * 16);    // 16 KB bf16 frag-order W2
    int*   bucket_cnt  = (int*)take(512 * 4);          // [0:256)=cnt, [256:512)=cur offsets
    int*   bucket_cur  = bucket_cnt + 256;

    hipMemsetAsync(bucket_cnt, 0, 512 * 4, stream);

    // 1) bucket hist + W prep (fused)
    k_hw<<<268, 256, 0, stream>>>(colv, bucket_cnt, W1, W2, w1f, w2f, E);

    // 2) edge partition || GEMM1-raw (fused, fully independent branches)
    int PB = (E + PSTAGE - 1) / PSTAGE;
    int gblocks = (N + 63) / 64;
    k_pg<<<PB + gblocks, 256, 0, stream>>>(rowv, colv, bucket_cnt, bucket_cur, ebuf,
                                           E, PB, x, w1f, g1b, N);

    // 3) per-bucket counting sort -> rowptr, dis, adj (1024-thread blocks)
    k_bfill<<<NB, 1024, 0, stream>>>(ebuf, bucket_cnt, rowptr, dis, adj, N, E);

    // 4-6) agg1 (per-src dis fma) -> gemm2 -> agg2 (4-deep)
    k_agg1<<<(N + 3) / 4, 256, 0, stream>>>((const uint4*)g1b, rowptr, adj, dis, b1,
                                            (uint4*)zb, N);
    k_gemm2<<<gblocks, 256, 0, stream>>>(zb, w2f, dis, g2b, N);
    k_agg2<<<(N + 3) / 4, 256, 0, stream>>>((const uint4*)g2b, rowptr, adj, dis, b2, out, N);
}

// Round 11
// 260.576 us; speedup vs baseline: 1.0451x; 1.0451x over previous
//
#include <hip/hip_runtime.h>

#define F1 128
#define F2 64
// bucket = 512 consecutive nodes; requires N <= 256*512 and N < 2^17 (u32 pack)
#define BSH 9
#define BSZ 512
// LDS staging capacity for one bucket's edge list in k_bfill (48 KB).
#define BFILL_CAP 12288
// edges staged per block in the partition branch of k_pg
#define PSTAGE 4096

typedef unsigned int u32;
typedef unsigned short u16;
typedef __attribute__((ext_vector_type(8))) short bf16x8;   // 8 bf16 (4 VGPRs)
typedef __attribute__((ext_vector_type(4))) float f32x4;

// bf16 helpers (manual, header-version-proof). RNE pack, shift unpack.
__device__ __forceinline__ u32 bf16rne(float f) {
    u32 u = __float_as_uint(f);
    return (u + 0x7FFFu + ((u >> 16) & 1u)) >> 16;
}
__device__ __forceinline__ u32 pack2(float lo, float hi) {
    return bf16rne(lo) | (bf16rne(hi) << 16);
}
__device__ __forceinline__ float bflo(u32 u) { return __uint_as_float(u << 16); }
__device__ __forceinline__ float bfhi(u32 u) { return __uint_as_float(u & 0xFFFF0000u); }

__device__ __forceinline__ void acc8(float* ax, uint4 v) {
    ax[0] += bflo(v.x); ax[1] += bfhi(v.x);
    ax[2] += bflo(v.y); ax[3] += bfhi(v.y);
    ax[4] += bflo(v.z); ax[5] += bfhi(v.z);
    ax[6] += bflo(v.w); ax[7] += bfhi(v.w);
}

// ax += w * row  (per-source normalized accumulate)
__device__ __forceinline__ void facc8(float* ax, uint4 v, float w) {
    ax[0] = fmaf(w, bflo(v.x), ax[0]); ax[1] = fmaf(w, bfhi(v.x), ax[1]);
    ax[2] = fmaf(w, bflo(v.y), ax[2]); ax[3] = fmaf(w, bfhi(v.y), ax[3]);
    ax[4] = fmaf(w, bflo(v.z), ax[4]); ax[5] = fmaf(w, bfhi(v.z), ax[5]);
    ax[6] = fmaf(w, bflo(v.w), ax[6]); ax[7] = fmaf(w, bfhi(v.w), ax[7]);
}

// ---------------- W prep helper ----------------
// Frag layout for mfma_f32_16x16x32_bf16 B-operand: n = lane&15, k = (lane>>4)*8 + j.

__device__ __forceinline__ void wprep_do(const float* __restrict__ W,
                                         uint4* __restrict__ wf, int NBc, int t) {
    int lane = t & 63;
    int rem = t >> 6;
    int nb = rem % NBc;
    int kb = rem / NBc;
    int C = NBc * 16;
    int col = nb * 16 + (lane & 15);
    int krow = kb * 32 + (lane >> 4) * 8;
    u32 w[4];
#pragma unroll
    for (int p = 0; p < 4; p++) {
        float lo = W[(size_t)(krow + 2 * p) * C + col];
        float hi = W[(size_t)(krow + 2 * p + 1) * C + col];
        w[p] = pack2(lo, hi);
    }
    wf[t] = make_uint4(w[0], w[1], w[2], w[3]);
}

// ---------------- Fused: bucket histogram + W prep ----------------
// Blocks 0..255: bucket hist (LDS-aggregated). Blocks 256..267: W1/W2 prep.

__global__ __launch_bounds__(256) void k_hw(const int* __restrict__ colv,
                                            int* __restrict__ bucket_cnt,
                                            const float* __restrict__ W1,
                                            const float* __restrict__ W2,
                                            uint4* __restrict__ w1f,
                                            uint4* __restrict__ w2f, int E) {
    __shared__ int l[256];
    int blk = blockIdx.x;
    int t = threadIdx.x;
    if (blk < 256) {
        l[t] = 0;
        __syncthreads();
        for (int e = blk * 256 + t; e < E; e += 256 * 256)
            atomicAdd(&l[colv[e] >> BSH], 1);
        __syncthreads();
        if (l[t]) atomicAdd(&bucket_cnt[t], l[t]);
    } else {
        int b2 = blk - 256;
        if (b2 < 8) wprep_do(W1, w1f, 8, b2 * 256 + t);
        else        wprep_do(W2, w2f, 4, (b2 - 8) * 256 + t);
    }
}

// ---------------- Fused: edge partition (bucket sort) || GEMM1 (raw) ----------------
// Blocks [0, PB): stage PSTAGE edges, block-local counting sort by bucket into
// LDS, reserve per-bucket runs with one global atomic each, write runs out
// coalesced (bucket bases recomputed by scanning bucket_cnt). 16-edge runs
// (PSTAGE/256) give 64 B write granules.
// Blocks [PB, PB+gblocks): g1raw(bf16, row-major) = x @ W1 (UNSCALED -- the
// per-source dis scale is applied during agg1's gather, removing the CSR->gemm1
// dependency so the two branches overlap).

__global__ __launch_bounds__(256, 4) void k_pg(const int* __restrict__ rowv,
                                               const int* __restrict__ colv,
                                               const int* __restrict__ bucket_cnt,
                                               int* __restrict__ bucket_cur,
                                               u32* __restrict__ ebuf, int E, int PB,
                                               const float* __restrict__ x,
                                               const uint4* __restrict__ w1f,
                                               u16* __restrict__ gb, int N) {
    if ((int)blockIdx.x < PB) {
        __shared__ int lcnt[256], lexcl[256], lcur[256], lbase[256], gscan[256];
        __shared__ int stot;
        __shared__ u32 sval[PSTAGE];
        __shared__ u16 sbkt[PSTAGE];
        int t = threadIdx.x;
        lcnt[t] = 0;
        __syncthreads();
        int rows[16], cols[16];
        int e0 = blockIdx.x * PSTAGE;
#pragma unroll
        for (int it = 0; it < 16; it++) {
            int e = e0 + it * 256 + t;
            bool v = e < E;
            cols[it] = v ? colv[e] : -1;
            rows[it] = v ? rowv[e] : 0;
            if (v) atomicAdd(&lcnt[cols[it] >> BSH], 1);
        }
        int bc = bucket_cnt[t];
        __syncthreads();
        int v = lcnt[t];
        lexcl[t] = v;
        gscan[t] = bc;
        __syncthreads();
        for (int d = 1; d < 256; d <<= 1) {
            int u1 = (t >= d) ? lexcl[t - d] : 0;
            int u2 = (t >= d) ? gscan[t - d] : 0;
            __syncthreads();
            lexcl[t] += u1;
            gscan[t] += u2;
            __syncthreads();
        }
        int incl = lexcl[t];
        int gincl = gscan[t];
        __syncthreads();
        lexcl[t] = incl - v;
        lcur[t] = incl - v;
        if (v) lbase[t] = (gincl - bc) + atomicAdd(&bucket_cur[t], v);
        if (t == 255) stot = incl;
        __syncthreads();
#pragma unroll
        for (int it = 0; it < 16; it++) {
            if (cols[it] >= 0) {
                int b = cols[it] >> BSH;
                int pos = atomicAdd(&lcur[b], 1);
                sval[pos] = ((u32)(cols[it] & (BSZ - 1)) << 17) | (u32)rows[it];
                sbkt[pos] = (u16)b;
            }
        }
        __syncthreads();
        int total = stot;
        for (int i = t; i < total; i += 256) {
            int b = sbkt[i];
            ebuf[lbase[b] + (i - lexcl[b])] = sval[i];
        }
    } else {
        int bid = (int)blockIdx.x - PB;
        int lane = threadIdx.x & 63;
        int wave = threadIdx.x >> 6;
        int m = lane & 15, quad = lane >> 4;
        int row0 = bid * 64 + wave * 16;
        int arow = min(row0 + m, N - 1);
        const float* xr = x + (size_t)arow * F1 + quad * 8;
        bf16x8 a[4];
#pragma unroll
        for (int kb = 0; kb < 4; kb++) {
            float4 lo = *(const float4*)(xr + kb * 32);
            float4 hi = *(const float4*)(xr + kb * 32 + 4);
            a[kb][0] = (short)bf16rne(lo.x); a[kb][1] = (short)bf16rne(lo.y);
            a[kb][2] = (short)bf16rne(lo.z); a[kb][3] = (short)bf16rne(lo.w);
            a[kb][4] = (short)bf16rne(hi.x); a[kb][5] = (short)bf16rne(hi.y);
            a[kb][6] = (short)bf16rne(hi.z); a[kb][7] = (short)bf16rne(hi.w);
        }
        f32x4 acc[8];
#pragma unroll
        for (int nb = 0; nb < 8; nb++) acc[nb] = (f32x4)(0.0f);
#pragma unroll
        for (int nb = 0; nb < 8; nb++) {
#pragma unroll
            for (int kb = 0; kb < 4; kb++) {
                uint4 braw = w1f[(kb * 8 + nb) * 64 + lane];
                bf16x8 bf = *(bf16x8*)&braw;
                acc[nb] = __builtin_amdgcn_mfma_f32_16x16x32_bf16(a[kb], bf, acc[nb], 0, 0, 0);
            }
        }
        // epilogue: C layout col = lane&15, row = quad*4 + reg; raw (no dis)
        int rbase = row0 + quad * 4;
#pragma unroll
        for (int reg = 0; reg < 4; reg++) {
            int r = rbase + reg;
            if (r < N) {
                u16* gr = gb + (size_t)r * F1 + m;
#pragma unroll
                for (int nb = 0; nb < 8; nb++)
                    gr[nb * 16] = (u16)bf16rne(acc[nb][reg]);
            }
        }
    }
}

// ---------------- bfill: per-bucket counting sort -> rowptr, dis, adj ----------------
// One 1024-thread block per bucket (edge loops 2x wider than the 512 version;
// scans guarded to the first 512/256 threads).

__global__ __launch_bounds__(1024) void k_bfill(const u32* __restrict__ ebuf,
                                                const int* __restrict__ bucket_cnt,
                                                int* __restrict__ rowptr,
                                                float* __restrict__ dis,
                                                int* __restrict__ adj, int N, int E) {
    __shared__ int cnt[BSZ], scn[BSZ], cur[BSZ];
    __shared__ int bb[256];
    __shared__ int sadj[BFILL_CAP];
    int t = threadIdx.x;
    int b = blockIdx.x;
    if (t < 256) bb[t] = bucket_cnt[t];
    if (t < BSZ) cnt[t] = 0;
    __syncthreads();
    for (int d = 1; d < 256; d <<= 1) {
        int u = (t >= d && t < 256) ? bb[t - d] : 0;
        __syncthreads();
        if (t < 256) bb[t] += u;
        __syncthreads();
    }
    int e1 = bb[b];
    int e0 = e1 - bucket_cnt[b];
    int len = e1 - e0;
    if (b == 0 && t == 0) rowptr[N] = E;
    for (int i = e0 + t; i < e1; i += 1024)
        atomicAdd(&cnt[ebuf[i] >> 17], 1);
    __syncthreads();
    if (t < BSZ) scn[t] = cnt[t];
    __syncthreads();
    for (int d = 1; d < BSZ; d <<= 1) {
        int u = (t >= d && t < BSZ) ? scn[t - d] : 0;
        __syncthreads();
        if (t < BSZ) scn[t] += u;
        __syncthreads();
    }
    if (t < BSZ) {
        int excl = scn[t] - cnt[t];
        cur[t] = excl;
        int node = (b << BSH) + t;
        if (node < N) {
            rowptr[node] = e0 + excl;
            dis[node] = rsqrtf((float)(cnt[t] + 1));   // +1 self loop
        }
    }
    __syncthreads();
    if (len <= BFILL_CAP) {
        for (int i = e0 + t; i < e1; i += 1024) {
            u32 p = ebuf[i];
            int c = p >> 17;
            int pos = atomicAdd(&cur[c], 1);
            sadj[pos] = (int)(p & 0x1FFFFu);
        }
        __syncthreads();
        for (int i = t; i < len; i += 1024)
            adj[e0 + i] = sadj[i];
    } else {
        for (int i = e0 + t; i < e1; i += 1024) {
            u32 p = ebuf[i];
            int c = p >> 17;
            int pos = atomicAdd(&cur[c], 1);
            adj[e0 + pos] = (int)(p & 0x1FFFFu);
        }
    }
}

// ---------------- Aggregation 1: z = relu(dis_i*(dis_i*g1raw[i] + sum dis_src*g1raw[src]) + b1) ----------------
// Wave = 1 node. 4 lane-groups of 16; each group gathers one full 256B source
// row (16 lanes x uint4) and its source's dis (4B broadcast). 2 chunks in
// flight, exec-masked, adj+dis prefetch (plain loads -- NT hints measured
// harmful here, round 10). Cross-group reduce: shfl_xor 16, 32.

__global__ __launch_bounds__(256) void k_agg1(const uint4* __restrict__ g1,
                                              const int* __restrict__ rowptr,
                                              const int* __restrict__ adj,
                                              const float* __restrict__ dis,
                                              const float* __restrict__ b,
                                              uint4* __restrict__ z, int N) {
    int node = __builtin_amdgcn_readfirstlane(blockIdx.x * 4 + (threadIdx.x >> 6));
    if (node >= N) return;
    int lane = threadIdx.x & 63;
    int grp = lane >> 4;        // 0..3
    int sub = lane & 15;        // col chunk: cols [8*sub, 8*sub+8)
    float ax[8];
#pragma unroll
    for (int i = 0; i < 8; i++) ax[i] = 0.0f;
    int s = rowptr[node], e = rowptr[node + 1];
    float dnode = dis[node];
    if (grp == 0) facc8(ax, g1[(size_t)node * 16 + sub], dnode);   // self-loop term
    const uint4 z4 = make_uint4(0u, 0u, 0u, 0u);
    int i0 = s + grp;
    bool p0 = i0 < e, p1 = i0 + 4 < e, p2 = i0 + 8 < e, p3 = i0 + 12 < e;
    int c0 = 0, c1 = 0, c2 = 0, c3 = 0;
    float d0 = 0.0f, d1 = 0.0f, d2 = 0.0f, d3 = 0.0f;
    if (p0) { c0 = adj[i0];      d0 = dis[c0]; }
    if (p1) { c1 = adj[i0 + 4];  d1 = dis[c1]; }
    if (p2) { c2 = adj[i0 + 8];  d2 = dis[c2]; }
    if (p3) { c3 = adj[i0 + 12]; d3 = dis[c3]; }
    for (int j = s; j < e; j += 16) {
        uint4 v0 = z4, v1 = z4, v2 = z4, v3 = z4;
        if (p0) v0 = g1[(size_t)c0 * 16 + sub];
        if (p1) v1 = g1[(size_t)c1 * 16 + sub];
        if (p2) v2 = g1[(size_t)c2 * 16 + sub];
        if (p3) v3 = g1[(size_t)c3 * 16 + sub];
        float w0 = d0, w1 = d1, w2 = d2, w3 = d3;
        int in0 = j + 16 + grp;
        p0 = in0 < e; p1 = in0 + 4 < e; p2 = in0 + 8 < e; p3 = in0 + 12 < e;
        d0 = 0.0f; d1 = 0.0f; d2 = 0.0f; d3 = 0.0f;
        if (p0) { c0 = adj[in0];      d0 = dis[c0]; }
        if (p1) { c1 = adj[in0 + 4];  d1 = dis[c1]; }
        if (p2) { c2 = adj[in0 + 8];  d2 = dis[c2]; }
        if (p3) { c3 = adj[in0 + 12]; d3 = dis[c3]; }
        facc8(ax, v0, w0);
        facc8(ax, v1, w1);
        facc8(ax, v2, w2);
        facc8(ax, v3, w3);
    }
#pragma unroll
    for (int i = 0; i < 8; i++) {
        ax[i] += __shfl_xor(ax[i], 16);
        ax[i] += __shfl_xor(ax[i], 32);
    }
    if (grp == 0) {
        float4 b0 = *(const float4*)(b + 8 * sub);
        float4 b1 = *(const float4*)(b + 8 * sub + 4);
        float o[8];
        o[0] = fmaxf(fmaf(dnode, ax[0], b0.x), 0.0f);
        o[1] = fmaxf(fmaf(dnode, ax[1], b0.y), 0.0f);
        o[2] = fmaxf(fmaf(dnode, ax[2], b0.z), 0.0f);
        o[3] = fmaxf(fmaf(dnode, ax[3], b0.w), 0.0f);
        o[4] = fmaxf(fmaf(dnode, ax[4], b1.x), 0.0f);
        o[5] = fmaxf(fmaf(dnode, ax[5], b1.y), 0.0f);
        o[6] = fmaxf(fmaf(dnode, ax[6], b1.z), 0.0f);
        o[7] = fmaxf(fmaf(dnode, ax[7], b1.w), 0.0f);
        uint4 ov;
        ov.x = pack2(o[0], o[1]); ov.y = pack2(o[2], o[3]);
        ov.z = pack2(o[4], o[5]); ov.w = pack2(o[6], o[7]);
        z[(size_t)node * 16 + sub] = ov;
    }
}

// ---------------- GEMM 2 (MFMA): g2(bf16, row-major) = dis[row] * (z @ W2) ----------------

__global__ __launch_bounds__(256, 4) void k_gemm2(const u32* __restrict__ z,
                                                  const uint4* __restrict__ w2f,
                                                  const float* __restrict__ dis,
                                                  u16* __restrict__ gb, int N) {
    int lane = threadIdx.x & 63;
    int wave = threadIdx.x >> 6;
    int m = lane & 15, quad = lane >> 4;
    int row0 = blockIdx.x * 64 + wave * 16;
    int arow = min(row0 + m, N - 1);
    const u32* zr = z + (size_t)arow * 64 + quad * 4;
    bf16x8 a[4];
#pragma unroll
    for (int kb = 0; kb < 4; kb++) {
        uint4 za = *(const uint4*)(zr + kb * 16);
        a[kb] = *(bf16x8*)&za;
    }
    f32x4 acc[4];
#pragma unroll
    for (int nb = 0; nb < 4; nb++) acc[nb] = (f32x4)(0.0f);
#pragma unroll
    for (int nb = 0; nb < 4; nb++) {
#pragma unroll
        for (int kb = 0; kb < 4; kb++) {
            uint4 braw = w2f[(kb * 4 + nb) * 64 + lane];
            bf16x8 bf = *(bf16x8*)&braw;
            acc[nb] = __builtin_amdgcn_mfma_f32_16x16x32_bf16(a[kb], bf, acc[nb], 0, 0, 0);
        }
    }
    float dv[4];
    int rbase = row0 + quad * 4;
#pragma unroll
    for (int reg = 0; reg < 4; reg++) dv[reg] = dis[min(rbase + reg, N - 1)];
#pragma unroll
    for (int reg = 0; reg < 4; reg++) {
        int r = rbase + reg;
        if (r < N) {
            u16* gr = gb + (size_t)r * F2 + m;
#pragma unroll
            for (int nb = 0; nb < 4; nb++)
                gr[nb * 16] = (u16)bf16rne(acc[nb][reg] * dv[reg]);
        }
    }
}

// ---------------- Aggregation 2: out(fp32) = dis[i]*(g2[i] + sum g2[src]) + b2 ----------------
// Wave = 1 node. 8 lane-groups of 8; each group gathers one 128B source row.
// 4 chunks (32 edges) in flight, exec-masked, plain adj prefetch.
// Reduce: shfl_xor 8, 16, 32.

__global__ __launch_bounds__(256) void k_agg2(const uint4* __restrict__ g,
                                              const int* __restrict__ rowptr,
                                              const int* __restrict__ adj,
                                              const float* __restrict__ dis,
                                              const float* __restrict__ b,
                                              float* __restrict__ out, int N) {
    int node = __builtin_amdgcn_readfirstlane(blockIdx.x * 4 + (threadIdx.x >> 6));
    if (node >= N) return;
    int lane = threadIdx.x & 63;
    int grp = lane >> 3;        // 0..7
    int sub = lane & 7;         // col chunk: cols [8*sub, 8*sub+8)
    float ax[8];
#pragma unroll
    for (int i = 0; i < 8; i++) ax[i] = 0.0f;
    int s = rowptr[node], e = rowptr[node + 1];
    if (grp == 0) acc8(ax, g[(size_t)node * 8 + sub]);   // self-loop term
    const uint4 z4 = make_uint4(0u, 0u, 0u, 0u);
    int i0 = s + grp;
    bool p0 = i0 < e, p1 = i0 + 8 < e, p2 = i0 + 16 < e, p3 = i0 + 24 < e;
    int c0 = 0, c1 = 0, c2 = 0, c3 = 0;
    if (p0) c0 = adj[i0];
    if (p1) c1 = adj[i0 + 8];
    if (p2) c2 = adj[i0 + 16];
    if (p3) c3 = adj[i0 + 24];
    for (int j = s; j < e; j += 32) {
        uint4 v0 = z4, v1 = z4, v2 = z4, v3 = z4;
        if (p0) v0 = g[(size_t)c0 * 8 + sub];
        if (p1) v1 = g[(size_t)c1 * 8 + sub];
        if (p2) v2 = g[(size_t)c2 * 8 + sub];
        if (p3) v3 = g[(size_t)c3 * 8 + sub];
        int in0 = j + 32 + grp;
        p0 = in0 < e; p1 = in0 + 8 < e; p2 = in0 + 16 < e; p3 = in0 + 24 < e;
        if (p0) c0 = adj[in0];
        if (p1) c1 = adj[in0 + 8];
        if (p2) c2 = adj[in0 + 16];
        if (p3) c3 = adj[in0 + 24];
        acc8(ax, v0);
        acc8(ax, v1);
        acc8(ax, v2);
        acc8(ax, v3);
    }
#pragma unroll
    for (int i = 0; i < 8; i++) {
        ax[i] += __shfl_xor(ax[i], 8);
        ax[i] += __shfl_xor(ax[i], 16);
        ax[i] += __shfl_xor(ax[i], 32);
    }
    if (grp == 0) {
        float d = dis[node];
        float4 b0 = *(const float4*)(b + 8 * sub);
        float4 b1 = *(const float4*)(b + 8 * sub + 4);
        float4 o0, o1;
        o0.x = fmaf(d, ax[0], b0.x); o0.y = fmaf(d, ax[1], b0.y);
        o0.z = fmaf(d, ax[2], b0.z); o0.w = fmaf(d, ax[3], b0.w);
        o1.x = fmaf(d, ax[4], b1.x); o1.y = fmaf(d, ax[5], b1.y);
        o1.z = fmaf(d, ax[6], b1.z); o1.w = fmaf(d, ax[7], b1.w);
        float4* op = (float4*)(out + (size_t)node * F2 + 8 * sub);
        op[0] = o0;
        op[1] = o1;
    }
}

// ---------------- launch ----------------

extern "C" void kernel_launch(void* const* d_in, const int* in_sizes, int n_in,
                              void* d_out, int out_size, void* d_ws, size_t ws_size,
                              hipStream_t stream) {
    const float* x  = (const float*)d_in[0];
    const int*   ei = (const int*)d_in[1];
    const float* W1 = (const float*)d_in[2];
    const float* b1 = (const float*)d_in[3];
    const float* W2 = (const float*)d_in[4];
    const float* b2 = (const float*)d_in[5];
    float* out = (float*)d_out;

    const int N = in_sizes[0] / F1;
    const int E = in_sizes[1] / 2;
    const int NB = (N + BSZ - 1) >> BSH;   // 196 for N=100000; must be <= 256
    const int* rowv = ei;        // sources
    const int* colv = ei + E;    // targets

    char* ws = (char*)d_ws;
    size_t off = 0;
    auto take = [&](size_t bytes) -> void* {
        void* p = ws + off;
        off += (bytes + 255) & ~(size_t)255;
        return p;
    };
    u16*   g1b     = (u16*)take((size_t)N * F1 * 2);   // 25.6 MB (bf16 row-major, RAW x@W1)
    u32*   zb      = (u32*)take((size_t)N * 64 * 4);   // 25.6 MB (bf16 packed)
    u16*   g2b     = g1b;                // g1 dead after agg1 -> reuse
    u32*   ebuf    = zb;                 // ebuf (6.4 MB) dead before agg1 writes zb;
                                         // separate from g1b (gemm1 runs concurrent with part)
    float* dis     = (float*)take((size_t)N * 4);
    int*   rowptr  = (int*)take((size_t)(N + 1) * 4);
    int*   adj     = (int*)take((size_t)E * 4);        // 6.4 MB
    uint4* w1f     = (uint4*)take(4 * 8 * 64 * 16);    // 32 KB bf16 frag-order W1
    uint4* w2f     = (uint4*)take(4 * 4 * 64 * 16);    // 16 KB bf16 frag-order W2
    int*   bucket_cnt  = (int*)take(512 * 4);          // [0:256)=cnt, [256:512)=cur offsets
    int*   bucket_cur  = bucket_cnt + 256;

    hipMemsetAsync(bucket_cnt, 0, 512 * 4, stream);

    // 1) bucket hist + W prep (fused)
    k_hw<<<268, 256, 0, stream>>>(colv, bucket_cnt, W1, W2, w1f, w2f, E);

    // 2) edge partition || GEMM1-raw (fused, fully independent branches)
    int PB = (E + PSTAGE - 1) / PSTAGE;
    int gblocks = (N + 63) / 64;
    k_pg<<<PB + gblocks, 256, 0, stream>>>(rowv, colv, bucket_cnt, bucket_cur, ebuf,
                                           E, PB, x, w1f, g1b, N);

    // 3) per-bucket counting sort -> rowptr, dis, adj (1024-thread blocks)
    k_bfill<<<NB, 1024, 0, stream>>>(ebuf, bucket_cnt, rowptr, dis, adj, N, E);

    // 4-6) agg1 (per-src dis fma) -> gemm2 -> agg2 (4-deep)
    k_agg1<<<(N + 3) / 4, 256, 0, stream>>>((const uint4*)g1b, rowptr, adj, dis, b1,
                                            (uint4*)zb, N);
    k_gemm2<<<gblocks, 256, 0, stream>>>(zb, w2f, dis, g2b, N);
    k_agg2<<<(N + 3) / 4, 256, 0, stream>>>((const uint4*)g2b, rowptr, adj, dis, b2, out, N);
}